// Round 1
// baseline (505.331 us; speedup 1.0000x reference)
//
#include <hip/hip_runtime.h>

// Problem constants (from reference): V=C=8192, B=8, T=1024.
#define V 8192
#define B 8
#define T 1024
#define NSEG 16          // T split into 16 segments of 64
#define SEGLEN 64
#define CSLICE 1024      // channels per gather block (256 thr * float4)
#define NCHUNK 32        // LSE chunks of 256 channels (64 lanes * float4)
#define CHUNK 256

// Kernel 1: gather logits[b,t,:] = emb[x[b,t],:] and accumulate per-segment
// per-channel sums (first level of the two-level cumsum).
// grid (V/CSLICE=8, NSEG=16, B=8), block 256.
__global__ __launch_bounds__(256) void gather_kernel(
    const float* __restrict__ emb, const int* __restrict__ x,
    float* __restrict__ logits, float* __restrict__ segsum)
{
    const int slice = blockIdx.x;
    const int seg   = blockIdx.y;
    const int b     = blockIdx.z;
    const int c4    = (slice * CSLICE + threadIdx.x * 4) >> 2;   // float4 index in row

    const float4* emb4    = (const float4*)emb;
    float4*       logits4 = (float4*)logits;

    float4 acc = make_float4(0.f, 0.f, 0.f, 0.f);
#pragma unroll 4
    for (int i = 0; i < SEGLEN; ++i) {
        const int t   = seg * SEGLEN + i;
        const int row = x[b * T + t];                 // uniform -> scalar load
        float4 v = emb4[(size_t)row * (V / 4) + c4];
        logits4[(size_t)(b * T + t) * (V / 4) + c4] = v;
        acc.x += v.x; acc.y += v.y; acc.z += v.z; acc.w += v.w;
    }
    ((float4*)segsum)[(size_t)(b * NSEG + seg) * (V / 4) + c4] = acc;
}

// Kernel 2: per (b, 256-ch chunk, 64-t segment) wave: carry-in from segment
// sums, then sequential running-sum walk emitting partial exp-sums per t and
// the target value m[y] when this wave owns channel y[b,t].
// grid (NCHUNK=32, NSEG=16, B=8), block 64 (one wave).
__global__ __launch_bounds__(64) void lse_kernel(
    const float* __restrict__ logits, const float* __restrict__ segsum,
    const int* __restrict__ y, float* __restrict__ P, float* __restrict__ tval)
{
    const int chunk = blockIdx.x;
    const int seg   = blockIdx.y;
    const int b     = blockIdx.z;
    const int lane  = threadIdx.x;
    const int c0    = chunk * CHUNK + lane * 4;
    const int c4    = c0 >> 2;

    const float4* ss4 = (const float4*)segsum;
    float4 S = make_float4(0.f, 0.f, 0.f, 0.f);
    for (int s = 0; s < seg; ++s) {                   // carry-in (exclusive scan)
        float4 v = ss4[(size_t)(b * NSEG + s) * (V / 4) + c4];
        S.x += v.x; S.y += v.y; S.z += v.z; S.w += v.w;
    }

    const float4* logits4 = (const float4*)logits;
    for (int i = 0; i < SEGLEN; ++i) {
        const int t   = seg * SEGLEN + i;
        const int pos = b * T + t;
        float4 v = logits4[(size_t)pos * (V / 4) + c4];
        S.x += v.x; S.y += v.y; S.z += v.z; S.w += v.w;
        const float inv = 1.0f / (float)(t + 1);
        const float m0 = S.x * inv, m1 = S.y * inv, m2 = S.z * inv, m3 = S.w * inv;
        float e = __expf(m0) + __expf(m1) + __expf(m2) + __expf(m3);

        const int yc = y[pos];                        // uniform
        const unsigned d = (unsigned)(yc - c0);
        if (d < 4u) {
            const float mv = (d == 0) ? m0 : (d == 1) ? m1 : (d == 2) ? m2 : m3;
            tval[pos] = mv;                           // unique writer
        }
#pragma unroll
        for (int off = 32; off; off >>= 1) e += __shfl_xor(e, off, 64);
        if (lane == 0) P[(size_t)chunk * (B * T) + pos] = e;
    }
}

// Kernel 3: per position sum chunk partials, nll = log(sum) - m[y]; mean via
// block reduce + one atomic per block. grid 32, block 256.
__global__ __launch_bounds__(256) void loss_kernel(
    const float* __restrict__ P, const float* __restrict__ tval,
    float* __restrict__ loss)
{
    const int pos = blockIdx.x * 256 + threadIdx.x;   // 0..8191
    float s = 0.f;
#pragma unroll
    for (int ch = 0; ch < NCHUNK; ++ch) s += P[(size_t)ch * (B * T) + pos];
    float nll = __logf(s) - tval[pos];

#pragma unroll
    for (int off = 32; off; off >>= 1) nll += __shfl_xor(nll, off, 64);
    __shared__ float red[4];
    const int wid = threadIdx.x >> 6;
    if ((threadIdx.x & 63) == 0) red[wid] = nll;
    __syncthreads();
    if (threadIdx.x == 0) {
        const float tot = red[0] + red[1] + red[2] + red[3];
        atomicAdd(loss, tot * (1.0f / (float)(B * T)));
    }
}

extern "C" void kernel_launch(void* const* d_in, const int* in_sizes, int n_in,
                              void* d_out, int out_size, void* d_ws, size_t ws_size,
                              hipStream_t stream) {
    const int*   x   = (const int*)d_in[0];
    const int*   y   = (const int*)d_in[1];
    const float* emb = (const float*)d_in[2];

    float* logits = (float*)d_out;                       // B*T*V floats
    float* loss   = logits + (size_t)B * T * V;          // 1 float

    // workspace layout: segsum [B][NSEG][V] (4 MB) | P [NCHUNK][B*T] (1 MB) | tval [B*T]
    float* segsum = (float*)d_ws;
    float* P      = segsum + (size_t)B * NSEG * V;
    float* tval   = P + (size_t)NCHUNK * B * T;

    gather_kernel<<<dim3(V / CSLICE, NSEG, B), 256, 0, stream>>>(emb, x, logits, segsum);
    lse_kernel<<<dim3(NCHUNK, NSEG, B), 64, 0, stream>>>(logits, segsum, y, P, tval);
    hipMemsetAsync(loss, 0, sizeof(float), stream);
    loss_kernel<<<dim3(B * T / 256), 256, 0, stream>>>(P, tval, loss);
}

// Round 2
// 484.925 us; speedup vs baseline: 1.0421x; 1.0421x over previous
//
#include <hip/hip_runtime.h>

// Problem constants (from reference): V=C=8192, B=8, T=1024.
#define V 8192
#define B 8
#define T 1024
#define NSEG 16          // T split into 16 segments of 64
#define SEGLEN 64
#define CSLICE 1024      // channels per sum-block (256 thr * float4)
#define NCHUNK 32        // LSE chunks of 256 channels (64 lanes * float4)
#define CHUNK 256

// Pass 1 (read-only): per-segment per-channel sums of the gathered rows.
// grid (V/CSLICE=8, NSEG=16, B=8), block 256. Reads emb rows (~162 MB
// distinct -> warms LLC), writes 4 MB segsum. No logits write here.
__global__ __launch_bounds__(256) void sum_kernel(
    const float* __restrict__ emb, const int* __restrict__ x,
    float* __restrict__ segsum)
{
    const int slice = blockIdx.x;
    const int seg   = blockIdx.y;
    const int b     = blockIdx.z;
    const int c4    = (slice * CSLICE + threadIdx.x * 4) >> 2;

    const float4* emb4 = (const float4*)emb;
    float4 acc = make_float4(0.f, 0.f, 0.f, 0.f);
#pragma unroll 4
    for (int i = 0; i < SEGLEN; ++i) {
        const int row = x[b * T + seg * SEGLEN + i];  // wave-uniform scalar
        float4 v = emb4[(size_t)row * (V / 4) + c4];
        acc.x += v.x; acc.y += v.y; acc.z += v.z; acc.w += v.w;
    }
    ((float4*)segsum)[(size_t)(b * NSEG + seg) * (V / 4) + c4] = acc;
}

// Pass 2 (fused gather + logits write + LSE): per wave = one (b, 256-ch
// chunk, 64-t segment). Carry-in from segsum, then walk the segment:
// re-gather emb (LLC-hot), WRITE logits, update running sum, exp, reduce.
// grid (NCHUNK/4=8, NSEG=16, B=8), block 256 (4 waves, wave=chunk sub-id).
__global__ __launch_bounds__(256) void fused_kernel(
    const float* __restrict__ emb, const int* __restrict__ x,
    const int* __restrict__ y, const float* __restrict__ segsum,
    float* __restrict__ logits, float* __restrict__ P, float* __restrict__ tval)
{
    const int wave  = threadIdx.x >> 6;
    const int lane  = threadIdx.x & 63;
    const int chunk = blockIdx.x * 4 + wave;          // 0..31
    const int seg   = blockIdx.y;
    const int b     = blockIdx.z;
    const int c0    = chunk * CHUNK + lane * 4;
    const int c4    = c0 >> 2;

    const float4* ss4 = (const float4*)segsum;
    float4 S = make_float4(0.f, 0.f, 0.f, 0.f);
    for (int s = 0; s < seg; ++s) {                   // exclusive carry-in
        float4 v = ss4[(size_t)(b * NSEG + s) * (V / 4) + c4];
        S.x += v.x; S.y += v.y; S.z += v.z; S.w += v.w;
    }

    const float4* emb4    = (const float4*)emb;
    float4*       logits4 = (float4*)logits;
    for (int i = 0; i < SEGLEN; ++i) {
        const int t   = seg * SEGLEN + i;
        const int pos = b * T + t;
        const int row = x[pos];                       // wave-uniform
        float4 v = emb4[(size_t)row * (V / 4) + c4];
        logits4[(size_t)pos * (V / 4) + c4] = v;
        S.x += v.x; S.y += v.y; S.z += v.z; S.w += v.w;
        const float inv = 1.0f / (float)(t + 1);
        const float m0 = S.x * inv, m1 = S.y * inv, m2 = S.z * inv, m3 = S.w * inv;
        float e = __expf(m0) + __expf(m1) + __expf(m2) + __expf(m3);

        const int yc = y[pos];                        // wave-uniform
        const unsigned d = (unsigned)(yc - c0);
        if (d < 4u) {
            const float mv = (d == 0) ? m0 : (d == 1) ? m1 : (d == 2) ? m2 : m3;
            tval[pos] = mv;                           // unique writer per pos
        }
#pragma unroll
        for (int off = 32; off; off >>= 1) e += __shfl_xor(e, off, 64);
        if (lane == 0) P[(size_t)chunk * (B * T) + pos] = e;
    }
}

// Pass 3: per position sum chunk partials, nll = log(sum) - m[y]; mean via
// block reduce + one atomic per block. grid 32, block 256.
__global__ __launch_bounds__(256) void loss_kernel(
    const float* __restrict__ P, const float* __restrict__ tval,
    float* __restrict__ loss)
{
    const int pos = blockIdx.x * 256 + threadIdx.x;   // 0..8191
    float s = 0.f;
#pragma unroll
    for (int ch = 0; ch < NCHUNK; ++ch) s += P[(size_t)ch * (B * T) + pos];
    float nll = __logf(s) - tval[pos];

#pragma unroll
    for (int off = 32; off; off >>= 1) nll += __shfl_xor(nll, off, 64);
    __shared__ float red[4];
    const int wid = threadIdx.x >> 6;
    if ((threadIdx.x & 63) == 0) red[wid] = nll;
    __syncthreads();
    if (threadIdx.x == 0) {
        const float tot = red[0] + red[1] + red[2] + red[3];
        atomicAdd(loss, tot * (1.0f / (float)(B * T)));
    }
}

extern "C" void kernel_launch(void* const* d_in, const int* in_sizes, int n_in,
                              void* d_out, int out_size, void* d_ws, size_t ws_size,
                              hipStream_t stream) {
    const int*   x   = (const int*)d_in[0];
    const int*   y   = (const int*)d_in[1];
    const float* emb = (const float*)d_in[2];

    float* logits = (float*)d_out;                       // B*T*V floats
    float* loss   = logits + (size_t)B * T * V;          // 1 float

    // workspace: segsum [B][NSEG][V] (4 MB) | P [NCHUNK][B*T] (1 MB) | tval [B*T]
    float* segsum = (float*)d_ws;
    float* P      = segsum + (size_t)B * NSEG * V;
    float* tval   = P + (size_t)NCHUNK * B * T;

    hipMemsetAsync(loss, 0, sizeof(float), stream);
    sum_kernel<<<dim3(V / CSLICE, NSEG, B), 256, 0, stream>>>(emb, x, segsum);
    fused_kernel<<<dim3(NCHUNK / 4, NSEG, B), 256, 0, stream>>>(emb, x, y, segsum, logits, P, tval);
    loss_kernel<<<dim3(B * T / 256), 256, 0, stream>>>(P, tval, loss);
}